// Round 3
// baseline (434.272 us; speedup 1.0000x reference)
//
#include <hip/hip_runtime.h>

#define KD 6
#define DD 3
#define CO 32
#define CI 32
#define KC (KD * CO)  // 192

// ---------------- kernel 1: xg = x @ g  ->  ws [N, 192] ----------------
__global__ void xg_kernel(const float* __restrict__ x, const float* __restrict__ g,
                          float* __restrict__ xg, int N) {
    __shared__ float gs[CI * KC];  // 24 KiB
    for (int i = threadIdx.x; i < CI * KC; i += blockDim.x) gs[i] = g[i];
    __syncthreads();
    int total = N * KC;  // 31.5M < 2^31
    for (int idx = blockIdx.x * blockDim.x + threadIdx.x; idx < total;
         idx += gridDim.x * blockDim.x) {
        int n = idx / KC;
        int j = idx - n * KC;
        const float* xr = x + n * CI;
        float acc = 0.f;
#pragma unroll
        for (int c = 0; c < CI; ++c) acc = fmaf(xr[c], gs[c * KC + j], acc);
        xg[idx] = acc;
    }
}

// ---------------- kernel 2: per-edge message + atomic scatter ----------------
// 32 lanes per edge; lane o owns output channel o.
__global__ void edge_kernel(const int* __restrict__ ei, const float* __restrict__ pseudo,
                            const float* __restrict__ xg, const float* __restrict__ mu,
                            const float* __restrict__ sigma,
                            float* __restrict__ agg, float* __restrict__ cnt, int E) {
    // fold mu/sigma into registers: iv = -0.5/(eps + sigma^2)
    float m[KD][DD], iv[KD][DD];
#pragma unroll
    for (int k = 0; k < KD; ++k)
#pragma unroll
        for (int d = 0; d < DD; ++d) {
            m[k][d] = mu[k * DD + d];
            float s = sigma[k * DD + d];
            iv[k][d] = -0.5f / (1e-15f + s * s);
        }
    const int o = threadIdx.x & 31;
    const int gpb = blockDim.x >> 5;
    int e0 = blockIdx.x * gpb + (threadIdx.x >> 5);
    const int estride = gridDim.x * gpb;
    for (int e = e0; e < E; e += estride) {
        const int src = ei[e];
        const int dst = ei[E + e];
        const float p0 = pseudo[e * 3 + 0];
        const float p1 = pseudo[e * 3 + 1];
        const float p2 = pseudo[e * 3 + 2];
        const float* xr = xg + (long long)src * KC;
        float msg = 0.f;
#pragma unroll
        for (int k = 0; k < KD; ++k) {
            float d0 = p0 - m[k][0], d1 = p1 - m[k][1], d2 = p2 - m[k][2];
            float ex = d0 * d0 * iv[k][0] + d1 * d1 * iv[k][1] + d2 * d2 * iv[k][2];
            float w = __expf(ex);
            msg = fmaf(w, xr[k * CO + o], msg);
        }
        atomicAdd(&agg[(long long)dst * CO + o], msg);  // coalesced across 32 lanes
        if (o == 0) atomicAdd(&cnt[dst], 1.0f);
    }
}

// ---------------- kernel 3: out = agg/max(cnt,1) + x@root + bias ----------------
__global__ void out_kernel(const float* __restrict__ x, const float* __restrict__ root,
                           const float* __restrict__ bias, const float* __restrict__ cnt,
                           float* __restrict__ out, int N) {
    __shared__ float rs[CI * CO];  // 4 KiB
    __shared__ float bs[CO];
    for (int i = threadIdx.x; i < CI * CO; i += blockDim.x) rs[i] = root[i];
    if (threadIdx.x < CO) bs[threadIdx.x] = bias[threadIdx.x];
    __syncthreads();
    int total = N * CO;  // 5.24M
    for (int idx = blockIdx.x * blockDim.x + threadIdx.x; idx < total;
         idx += gridDim.x * blockDim.x) {
        int n = idx / CO;
        int o = idx - n * CO;
        const float* xr = x + n * CI;
        float acc = 0.f;
#pragma unroll
        for (int c = 0; c < CI; ++c) acc = fmaf(xr[c], rs[c * CO + o], acc);
        float cn = cnt[n];
        out[idx] = out[idx] / fmaxf(cn, 1.0f) + acc + bs[o];
    }
}

extern "C" void kernel_launch(void* const* d_in, const int* in_sizes, int n_in,
                              void* d_out, int out_size, void* d_ws, size_t ws_size,
                              hipStream_t stream) {
    const float* x      = (const float*)d_in[0];
    const int*   ei     = (const int*)d_in[1];
    const float* pseudo = (const float*)d_in[2];
    const float* g      = (const float*)d_in[3];
    const float* mu     = (const float*)d_in[4];
    const float* sigma  = (const float*)d_in[5];
    const float* root   = (const float*)d_in[6];
    const float* bias   = (const float*)d_in[7];
    float* out = (float*)d_out;

    const int N = in_sizes[0] / CI;
    const int E = in_sizes[1] / 2;

    float* xg  = (float*)d_ws;                 // N*192 floats = 125.8 MB
    float* cnt = xg + (size_t)N * KC;          // N floats

    // zero the accumulators (d_out doubles as agg; ws is poisoned 0xAA)
    hipMemsetAsync(d_out, 0, (size_t)out_size * sizeof(float), stream);
    hipMemsetAsync(cnt, 0, (size_t)N * sizeof(float), stream);

    const int blk = 256;

    int grid1 = (N * KC + blk - 1) / blk;
    if (grid1 > 4096) grid1 = 4096;
    xg_kernel<<<grid1, blk, 0, stream>>>(x, g, xg, N);

    const int gpb = blk / 32;
    int grid2 = (E + gpb - 1) / gpb;
    if (grid2 > 16384) grid2 = 16384;
    edge_kernel<<<grid2, blk, 0, stream>>>(ei, pseudo, xg, mu, sigma, out, cnt, E);

    int grid3 = (N * CO + blk - 1) / blk;
    if (grid3 > 4096) grid3 = 4096;
    out_kernel<<<grid3, blk, 0, stream>>>(x, root, bias, cnt, out, N);
}